// Round 1
// baseline (357.540 us; speedup 1.0000x reference)
//
#include <hip/hip_runtime.h>
#include <math.h>

// Problem constants
#define NPIX   131072      // B*H*W = 32*64*64
#define KEMB   512
#define DDIM   64
#define HW     4096        // H*W
#define BSTRIDE 262144     // C*H*W = 64*4096 (batch stride in input/out tensors)

// d_out flat layout (float32): [loss(1) | out(8388608) | perplexity(1) | indices(131072)]
#define OUT_OFF  1
#define PERP_OFF 8388609
#define IDX_OFF  8388610

// d_ws layout: [0..511] int counts | [512..1023] float norms | [1024] float loss accum
__global__ void vq_init(const float* __restrict__ emb, int* __restrict__ counts,
                        float* __restrict__ norms, float* __restrict__ loss_acc) {
    int k = threadIdx.x;            // 512 threads
    counts[k] = 0;
    const float4* row = (const float4*)(emb + k * DDIM);
    float s = 0.f;
#pragma unroll
    for (int i = 0; i < 16; ++i) {
        float4 v = row[i];
        s += v.x * v.x + v.y * v.y + v.z * v.z + v.w * v.w;
    }
    norms[k] = s;
    if (k == 0) *loss_acc = 0.f;
}

__global__ __launch_bounds__(256) void vq_main(
    const float* __restrict__ in,      // (B,C,H,W) fp32
    const float* __restrict__ emb,     // (K,D) fp32
    const float* __restrict__ norms,   // (K)
    int*  __restrict__ counts,         // (K) global histogram
    float* __restrict__ loss_acc,      // scalar accumulator
    float* __restrict__ dout)          // full output buffer
{
    __shared__ int hist[KEMB];
    const int t = threadIdx.x;
    hist[t] = 0; hist[t + 256] = 0;
    __syncthreads();

    const int b = blockIdx.x >> 4;                  // 16 blocks per batch image
    const int p = ((blockIdx.x & 15) << 8) | t;     // pixel index h*64+w within image
    const int inbase = b * BSTRIDE + p;

    // Load this pixel's 64 channels (stride HW per channel; coalesced across lanes)
    float x[DDIM];
#pragma unroll
    for (int c = 0; c < DDIM; ++c) x[c] = in[inbase + c * HW];

    // ||x||^2 with 4-way partial sums
    float n0 = 0.f, n1 = 0.f, n2 = 0.f, n3 = 0.f;
#pragma unroll
    for (int c = 0; c < DDIM; c += 4) {
        n0 = fmaf(x[c + 0], x[c + 0], n0);
        n1 = fmaf(x[c + 1], x[c + 1], n1);
        n2 = fmaf(x[c + 2], x[c + 2], n2);
        n3 = fmaf(x[c + 3], x[c + 3], n3);
    }
    const float xn = (n0 + n1) + (n2 + n3);

    // Argmin over K codes. emb row index k is wave-uniform -> scalar loads.
    float best = 3.402823466e38f;
    int bestk = 0;
#pragma unroll 2
    for (int k = 0; k < KEMB; ++k) {
        const float* __restrict__ e = emb + k * DDIM;
        float a0 = 0.f, a1 = 0.f, a2 = 0.f, a3 = 0.f;
#pragma unroll
        for (int c = 0; c < DDIM; c += 4) {
            a0 = fmaf(x[c + 0], e[c + 0], a0);
            a1 = fmaf(x[c + 1], e[c + 1], a1);
            a2 = fmaf(x[c + 2], e[c + 2], a2);
            a3 = fmaf(x[c + 3], e[c + 3], a3);
        }
        const float d = xn + norms[k] - 2.f * ((a0 + a1) + (a2 + a3));
        if (d < best) { best = d; bestk = k; }
    }

    // Write index (as float32 — d_out is one flat fp32 buffer)
    dout[IDX_OFF + b * HW + p] = (float)bestk;

    // Gather chosen code, write straight-through output, accumulate loss
    const float4* q = (const float4*)(emb + bestk * DDIM);
    float* outq = dout + OUT_OFF + b * BSTRIDE + p;
    float lsum = 0.f;
#pragma unroll
    for (int i = 0; i < 16; ++i) {
        float4 qv = q[i];
        const int c = i * 4;
        float d0 = qv.x - x[c + 0];
        float d1 = qv.y - x[c + 1];
        float d2 = qv.z - x[c + 2];
        float d3 = qv.w - x[c + 3];
        lsum += d0 * d0 + d1 * d1 + d2 * d2 + d3 * d3;
        // match reference rounding: x + (q - x)
        outq[(c + 0) * HW] = x[c + 0] + d0;
        outq[(c + 1) * HW] = x[c + 1] + d1;
        outq[(c + 2) * HW] = x[c + 2] + d2;
        outq[(c + 3) * HW] = x[c + 3] + d3;
    }

    // Per-block histogram then one global atomic per touched bin
    atomicAdd(&hist[bestk], 1);

    // Wave-level loss reduction (wave = 64 lanes)
    for (int off = 32; off > 0; off >>= 1) lsum += __shfl_down(lsum, off, 64);
    if ((t & 63) == 0) atomicAdd(loss_acc, lsum);

    __syncthreads();
    for (int k = t; k < KEMB; k += 256) {
        int v = hist[k];
        if (v) atomicAdd(&counts[k], v);
    }
}

__global__ void vq_fin(const int* __restrict__ counts,
                       const float* __restrict__ loss_acc,
                       float* __restrict__ dout) {
    __shared__ float red[KEMB];
    int k = threadIdx.x;            // 512 threads
    float c = (float)counts[k];
    float pa = c / (float)NPIX;
    red[k] = pa * logf(pa + 1e-10f);
    __syncthreads();
    for (int s = 256; s > 0; s >>= 1) {
        if (k < s) red[k] += red[k + s];
        __syncthreads();
    }
    if (k == 0) {
        dout[PERP_OFF] = expf(-red[0]);
        dout[0] = 0.25f * (*loss_acc) / 8388608.0f;
    }
}

extern "C" void kernel_launch(void* const* d_in, const int* in_sizes, int n_in,
                              void* d_out, int out_size, void* d_ws, size_t ws_size,
                              hipStream_t stream) {
    const float* in  = (const float*)d_in[0];   // 8388608 elems
    const float* emb = (const float*)d_in[1];   // 32768 elems
    float* dout = (float*)d_out;
    int*   counts   = (int*)d_ws;
    float* norms    = (float*)d_ws + 512;
    float* loss_acc = (float*)d_ws + 1024;

    vq_init<<<1, 512, 0, stream>>>(emb, counts, norms, loss_acc);
    vq_main<<<512, 256, 0, stream>>>(in, emb, norms, counts, loss_acc, dout);
    vq_fin<<<1, 512, 0, stream>>>(counts, loss_acc, dout);
}

// Round 2
// 352.116 us; speedup vs baseline: 1.0154x; 1.0154x over previous
//
#include <hip/hip_runtime.h>
#include <math.h>

// Problem constants
#define NPIX   131072      // B*H*W = 32*64*64
#define KEMB   512
#define DDIM   64
#define HW     4096        // H*W
#define BSTRIDE 262144     // C*H*W = 64*4096 (batch stride in input/out tensors)

// d_out flat layout (float32): [loss(1) | out(8388608) | perplexity(1) | indices(131072)]
#define OUT_OFF  1
#define PERP_OFF 8388609
#define IDX_OFF  8388610

// d_ws layout: [0..511] int counts | [512..1023] float half-norms | [1024] float loss accum
__global__ void vq_init(const float* __restrict__ emb, int* __restrict__ counts,
                        float* __restrict__ hnorms, float* __restrict__ loss_acc) {
    int k = threadIdx.x;            // 512 threads
    counts[k] = 0;
    const float4* row = (const float4*)(emb + k * DDIM);
    float s = 0.f;
#pragma unroll
    for (int i = 0; i < 16; ++i) {
        float4 v = row[i];
        s += v.x * v.x + v.y * v.y + v.z * v.z + v.w * v.w;
    }
    hnorms[k] = 0.5f * s;
    if (k == 0) *loss_acc = 0.f;
}

// block=256, min 2 waves/EU -> VGPR cap 256: x[64] MUST stay register-resident.
__global__ __launch_bounds__(256, 2) void vq_main(
    const float* __restrict__ in,      // (B,C,H,W) fp32
    const float* __restrict__ emb,     // (K,D) fp32
    const float* __restrict__ hnorms,  // (K) 0.5*||e||^2
    int*  __restrict__ counts,         // (K) global histogram
    float* __restrict__ loss_acc,      // scalar accumulator
    float* __restrict__ dout)          // full output buffer
{
    __shared__ int hist[KEMB];
    const int t = threadIdx.x;
    hist[t] = 0; hist[t + 256] = 0;
    __syncthreads();

    const int b = blockIdx.x >> 4;                  // 16 blocks per batch image
    const int p = ((blockIdx.x & 15) << 8) | t;     // pixel index h*64+w within image
    const int inbase = b * BSTRIDE + p;

    // Load this pixel's 64 channels (stride HW per channel; coalesced across lanes).
    // Keep ALL of x in VGPRs for the entire k-loop.
    float x[DDIM];
#pragma unroll
    for (int c = 0; c < DDIM; ++c) x[c] = in[inbase + c * HW];

    // Argmin over K codes using d/2 - ||x||^2/2 = 0.5*||e||^2 - x.e
    // (monotone in the true distance; ||x||^2 term is constant per pixel).
    // emb row address is wave-uniform -> scalar s_load, FMA reads SGPR operand.
    float best = 3.402823466e38f;
    int bestk = 0;
#pragma unroll 2
    for (int k = 0; k < KEMB; ++k) {
        const float4* __restrict__ e4 = (const float4*)(emb + k * DDIM);
        float a0 = hnorms[k], a1 = 0.f, a2 = 0.f, a3 = 0.f;
#pragma unroll
        for (int i = 0; i < 16; ++i) {
            float4 ev = e4[i];
            const int c = i * 4;
            a0 = fmaf(-x[c + 0], ev.x, a0);
            a1 = fmaf(-x[c + 1], ev.y, a1);
            a2 = fmaf(-x[c + 2], ev.z, a2);
            a3 = fmaf(-x[c + 3], ev.w, a3);
        }
        const float d = (a0 + a1) + (a2 + a3);
        if (d < best) { best = d; bestk = k; }
    }

    // Write index (as float32 — d_out is one flat fp32 buffer)
    dout[IDX_OFF + b * HW + p] = (float)bestk;

    // Gather chosen code, write straight-through output, accumulate loss
    const float4* q = (const float4*)(emb + bestk * DDIM);
    float* outq = dout + OUT_OFF + b * BSTRIDE + p;
    float lsum = 0.f;
#pragma unroll
    for (int i = 0; i < 16; ++i) {
        float4 qv = q[i];
        const int c = i * 4;
        float d0 = qv.x - x[c + 0];
        float d1 = qv.y - x[c + 1];
        float d2 = qv.z - x[c + 2];
        float d3 = qv.w - x[c + 3];
        lsum += d0 * d0 + d1 * d1 + d2 * d2 + d3 * d3;
        // match reference rounding: x + (q - x)
        outq[(c + 0) * HW] = x[c + 0] + d0;
        outq[(c + 1) * HW] = x[c + 1] + d1;
        outq[(c + 2) * HW] = x[c + 2] + d2;
        outq[(c + 3) * HW] = x[c + 3] + d3;
    }

    // Per-block histogram then one global atomic per touched bin
    atomicAdd(&hist[bestk], 1);

    // Wave-level loss reduction (wave = 64 lanes)
    for (int off = 32; off > 0; off >>= 1) lsum += __shfl_down(lsum, off, 64);
    if ((t & 63) == 0) atomicAdd(loss_acc, lsum);

    __syncthreads();
    for (int k = t; k < KEMB; k += 256) {
        int v = hist[k];
        if (v) atomicAdd(&counts[k], v);
    }
}

__global__ void vq_fin(const int* __restrict__ counts,
                       const float* __restrict__ loss_acc,
                       float* __restrict__ dout) {
    __shared__ float red[KEMB];
    int k = threadIdx.x;            // 512 threads
    float c = (float)counts[k];
    float pa = c / (float)NPIX;
    red[k] = pa * logf(pa + 1e-10f);
    __syncthreads();
    for (int s = 256; s > 0; s >>= 1) {
        if (k < s) red[k] += red[k + s];
        __syncthreads();
    }
    if (k == 0) {
        dout[PERP_OFF] = expf(-red[0]);
        dout[0] = 0.25f * (*loss_acc) / 8388608.0f;
    }
}

extern "C" void kernel_launch(void* const* d_in, const int* in_sizes, int n_in,
                              void* d_out, int out_size, void* d_ws, size_t ws_size,
                              hipStream_t stream) {
    const float* in  = (const float*)d_in[0];   // 8388608 elems
    const float* emb = (const float*)d_in[1];   // 32768 elems
    float* dout = (float*)d_out;
    int*   counts   = (int*)d_ws;
    float* hnorms   = (float*)d_ws + 512;
    float* loss_acc = (float*)d_ws + 1024;

    vq_init<<<1, 512, 0, stream>>>(emb, counts, hnorms, loss_acc);
    vq_main<<<512, 256, 0, stream>>>(in, emb, hnorms, counts, loss_acc, dout);
    vq_fin<<<1, 512, 0, stream>>>(counts, loss_acc, dout);
}

// Round 4
// 251.999 us; speedup vs baseline: 1.4188x; 1.3973x over previous
//
#include <hip/hip_runtime.h>
#include <math.h>

// Problem constants
#define NPIX   131072      // B*H*W = 32*64*64
#define KEMB   512
#define DDIM   64
#define HW     4096        // H*W
#define BSTRIDE 262144     // C*H*W

// d_out flat layout (float32): [loss(1) | out(8388608) | perplexity(1) | indices(131072)]
#define OUT_OFF  1
#define PERP_OFF 8388609
#define IDX_OFF  8388610

typedef __attribute__((ext_vector_type(8))) short bf16x8;   // 8 bf16 = 4 VGPRs (MFMA A/B frag)
typedef __attribute__((ext_vector_type(4))) float f32x4;    // MFMA C/D frag

__device__ __forceinline__ unsigned short bf16_rtne(float f) {
    unsigned int u = __float_as_uint(f);
    u += 0x7FFFu + ((u >> 16) & 1u);
    return (unsigned short)(u >> 16);
}
__device__ __forceinline__ float bf16_to_f(unsigned short h) {
    return __uint_as_float(((unsigned int)h) << 16);
}

// ws layout: [0,2048) int counts | [2048,4096) float hnorms | [4096] loss |
//            [8192) ebh ushort[32768] | +64KB ebm | +64KB ebl
__global__ void vq_init(const float* __restrict__ emb, int* __restrict__ counts,
                        float* __restrict__ hnorms, float* __restrict__ loss_acc,
                        unsigned short* __restrict__ ebh, unsigned short* __restrict__ ebm,
                        unsigned short* __restrict__ ebl) {
    int k = threadIdx.x;            // 512 threads, one code each
    counts[k] = 0;
    // norm: EXACT same summation order as the R2-passing kernel (float4 chain)
    const float4* row4 = (const float4*)(emb + k * DDIM);
    float s = 0.f;
#pragma unroll
    for (int i = 0; i < 16; ++i) {
        float4 v = row4[i];
        s += v.x * v.x + v.y * v.y + v.z * v.z + v.w * v.w;
    }
    hnorms[k] = 0.5f * s;
    // triple bf16 split (Sterbenz-exact residuals)
    const float* row = emb + k * DDIM;
    for (int c = 0; c < DDIM; ++c) {
        float x = row[c];
        unsigned short h = bf16_rtne(x);
        float r1 = x - bf16_to_f(h);
        unsigned short m = bf16_rtne(r1);
        float r2 = r1 - bf16_to_f(m);
        unsigned short l = bf16_rtne(r2);
        ebh[k * DDIM + c] = h; ebm[k * DDIM + c] = m; ebl[k * DDIM + c] = l;
    }
    if (k == 0) *loss_acc = 0.f;
}

// Wave owns 64 pixels (4 B-tiles of N=16). Codes stream as A-tiles (M=16).
// Approx score = 0.5||e||^2 - x.e via triple-bf16 MFMA -> top-2 candidates,
// then exact fp32 rescore of the 2 candidates (matches np's fp32 decisions).
__global__ __launch_bounds__(256, 2) void vq_main(
    const float* __restrict__ in, const float* __restrict__ emb,
    const unsigned short* __restrict__ ebh, const unsigned short* __restrict__ ebm,
    const unsigned short* __restrict__ ebl,
    const float* __restrict__ hnorms, int* __restrict__ counts,
    float* __restrict__ loss_acc, float* __restrict__ dout)
{
    __shared__ int hist[KEMB];
    const int t = threadIdx.x;
    hist[t] = 0; hist[t + 256] = 0;
    __syncthreads();

    const int lane = t & 63;
    const int wid  = t >> 6;
    const int quad = lane >> 4;
    const int col  = lane & 15;
    const int b    = blockIdx.x >> 4;
    const int p0   = ((blockIdx.x & 15) << 8) | (wid << 6);   // first of 64 pixels
    const float* xb = in + b * BSTRIDE;

    // ---- Build x B-fragments: B[n=col][k=quad*8+j], xf[split][ptile][kstep] ----
    bf16x8 xf[3][4][2];
#pragma unroll
    for (int tt = 0; tt < 4; ++tt) {
#pragma unroll
        for (int s = 0; s < 2; ++s) {
            const int pp = p0 + tt * 16 + col;
            const int c0 = s * 32 + quad * 8;
            bf16x8 vh, vm, vl;
#pragma unroll
            for (int j = 0; j < 8; ++j) {
                float x = xb[(c0 + j) * HW + pp];
                unsigned short h = bf16_rtne(x);
                float r1 = x - bf16_to_f(h);
                unsigned short m = bf16_rtne(r1);
                float r2 = r1 - bf16_to_f(m);
                unsigned short l = bf16_rtne(r2);
                vh[j] = (short)h; vm[j] = (short)m; vl[j] = (short)l;
            }
            xf[0][tt][s] = vh; xf[1][tt][s] = vm; xf[2][tt][s] = vl;
        }
    }

    const int arow = col * DDIM + quad * 8;   // lane offset within a code-tile (ushorts)

    // top-2 tracking per pixel-tile (lex order on (value, index))
    float v1[4], v2[4]; int k1[4], k2[4];
#pragma unroll
    for (int tt = 0; tt < 4; ++tt) {
        v1[tt] = 3.402823466e38f; v2[tt] = 3.402823466e38f; k1[tt] = 0; k2[tt] = 0;
    }

    bf16x8 A[2][3][2];
#pragma unroll
    for (int s = 0; s < 2; ++s) {
        A[0][0][s] = *(const bf16x8*)(ebh + arow + s * 32);
        A[0][1][s] = *(const bf16x8*)(ebm + arow + s * 32);
        A[0][2][s] = *(const bf16x8*)(ebl + arow + s * 32);
    }

    for (int ct = 0; ct < 32; ++ct) {
        const int cur = ct & 1, nxt = cur ^ 1;
        if (ct < 31) {
            const int off = (ct + 1) * 16 * DDIM + arow;
#pragma unroll
            for (int s = 0; s < 2; ++s) {
                A[nxt][0][s] = *(const bf16x8*)(ebh + off + s * 32);
                A[nxt][1][s] = *(const bf16x8*)(ebm + off + s * 32);
                A[nxt][2][s] = *(const bf16x8*)(ebl + off + s * 32);
            }
        }
        f32x4 acc[4];
#pragma unroll
        for (int tt = 0; tt < 4; ++tt) acc[tt] = (f32x4){0.f, 0.f, 0.f, 0.f};
#pragma unroll
        for (int s = 0; s < 2; ++s) {
            const int pa[6] = {0, 0, 1, 0, 2, 1};   // hh, hm, mh, hl, lh, mm
            const int pb[6] = {0, 1, 0, 2, 0, 1};
#pragma unroll
            for (int q = 0; q < 6; ++q) {
#pragma unroll
                for (int tt = 0; tt < 4; ++tt) {
                    acc[tt] = __builtin_amdgcn_mfma_f32_16x16x32_bf16(
                        A[cur][pa[q]][s], xf[pb[q]][tt][s], acc[tt], 0, 0, 0);
                }
            }
        }
        const f32x4 hn = *(const f32x4*)(hnorms + ct * 16 + quad * 4);
#pragma unroll
        for (int tt = 0; tt < 4; ++tt) {
#pragma unroll
            for (int r = 0; r < 4; ++r) {
                const float sc = hn[r] - acc[tt][r];
                const int   kk = ct * 16 + quad * 4 + r;
                if (sc < v1[tt]) { v2[tt] = v1[tt]; k2[tt] = k1[tt]; v1[tt] = sc; k1[tt] = kk; }
                else if (sc < v2[tt]) { v2[tt] = sc; k2[tt] = kk; }
            }
        }
    }

    // Cross-quad top-2 merge (lanes l, l^16, l^32 share pixel-col)
#pragma unroll
    for (int tt = 0; tt < 4; ++tt) {
#pragma unroll
        for (int off = 16; off <= 32; off <<= 1) {
            float w1 = __shfl_xor(v1[tt], off, 64); int j1 = __shfl_xor(k1[tt], off, 64);
            float w2 = __shfl_xor(v2[tt], off, 64); int j2 = __shfl_xor(k2[tt], off, 64);
            bool aF = (v1[tt] < w1) || (v1[tt] == w1 && k1[tt] < j1);
            float t1 = aF ? v1[tt] : w1;  int u1 = aF ? k1[tt] : j1;
            float tl = aF ? w1 : v1[tt];  int ul = aF ? j1 : k1[tt];      // loser of firsts
            bool bS = (v2[tt] < w2) || (v2[tt] == w2 && k2[tt] < j2);
            float tc = bS ? v2[tt] : w2;  int uc = bS ? k2[tt] : j2;      // better of seconds
            bool lS = (tl < tc) || (tl == tc && ul < uc);
            v1[tt] = t1; k1[tt] = u1;
            v2[tt] = lS ? tl : tc; k2[tt] = lS ? ul : uc;
        }
    }
    const int kA = k1[quad], kB = k2[quad];   // lane's own pixel = p0 + lane
    const int pp = p0 + lane;

    // Reload x (fp32, coalesced) for exact rescore + epilogue
    float x[DDIM];
#pragma unroll
    for (int c = 0; c < DDIM; ++c) x[c] = xb[c * HW + pp];

    // Exact fp32 rescore: byte-identical math to the R2-passing kernel
    const float4* eA = (const float4*)(emb + kA * DDIM);
    const float4* eB = (const float4*)(emb + kB * DDIM);
    float a0 = hnorms[kA], a1 = 0.f, a2 = 0.f, a3 = 0.f;
    float b0 = hnorms[kB], b1 = 0.f, b2 = 0.f, b3 = 0.f;
#pragma unroll
    for (int i = 0; i < 16; ++i) {
        float4 ea = eA[i], eb = eB[i];
        const int c = i * 4;
        a0 = fmaf(-x[c + 0], ea.x, a0);
        a1 = fmaf(-x[c + 1], ea.y, a1);
        a2 = fmaf(-x[c + 2], ea.z, a2);
        a3 = fmaf(-x[c + 3], ea.w, a3);
        b0 = fmaf(-x[c + 0], eb.x, b0);
        b1 = fmaf(-x[c + 1], eb.y, b1);
        b2 = fmaf(-x[c + 2], eb.z, b2);
        b3 = fmaf(-x[c + 3], eb.w, b3);
    }
    const float dA = (a0 + a1) + (a2 + a3);
    const float dB = (b0 + b1) + (b2 + b3);
    const int myk = (dB < dA || (dB == dA && kB < kA)) ? kB : kA;

    dout[IDX_OFF + b * HW + pp] = (float)myk;
    atomicAdd(&hist[myk], 1);

    // Epilogue: gather chosen code, ST output + loss (reference rounding x+(q-x))
    const float4* qrow = (const float4*)(emb + myk * DDIM);
    float* ob = dout + OUT_OFF + b * BSTRIDE;
    float lsum = 0.f;
#pragma unroll
    for (int i = 0; i < 16; ++i) {
        float4 qv = qrow[i];
        const int c = i * 4;
        float d0 = qv.x - x[c + 0];
        float d1 = qv.y - x[c + 1];
        float d2 = qv.z - x[c + 2];
        float d3 = qv.w - x[c + 3];
        lsum += d0 * d0 + d1 * d1 + d2 * d2 + d3 * d3;
        ob[(c + 0) * HW + pp] = x[c + 0] + d0;
        ob[(c + 1) * HW + pp] = x[c + 1] + d1;
        ob[(c + 2) * HW + pp] = x[c + 2] + d2;
        ob[(c + 3) * HW + pp] = x[c + 3] + d3;
    }
    for (int off = 32; off > 0; off >>= 1) lsum += __shfl_down(lsum, off, 64);
    if (lane == 0) atomicAdd(loss_acc, lsum);

    __syncthreads();
    for (int k = t; k < KEMB; k += 256) {
        int v = hist[k];
        if (v) atomicAdd(&counts[k], v);
    }
}

__global__ void vq_fin(const int* __restrict__ counts,
                       const float* __restrict__ loss_acc,
                       float* __restrict__ dout) {
    __shared__ float red[KEMB];
    int k = threadIdx.x;            // 512 threads
    float c = (float)counts[k];
    float pa = c / (float)NPIX;
    red[k] = pa * logf(pa + 1e-10f);
    __syncthreads();
    for (int s = 256; s > 0; s >>= 1) {
        if (k < s) red[k] += red[k + s];
        __syncthreads();
    }
    if (k == 0) {
        dout[PERP_OFF] = expf(-red[0]);
        dout[0] = 0.25f * (*loss_acc) / 8388608.0f;
    }
}

extern "C" void kernel_launch(void* const* d_in, const int* in_sizes, int n_in,
                              void* d_out, int out_size, void* d_ws, size_t ws_size,
                              hipStream_t stream) {
    const float* in  = (const float*)d_in[0];   // 8388608 elems
    const float* emb = (const float*)d_in[1];   // 32768 elems
    float* dout = (float*)d_out;
    int*   counts   = (int*)d_ws;
    float* hnorms   = (float*)((char*)d_ws + 2048);
    float* loss_acc = (float*)((char*)d_ws + 4096);
    unsigned short* ebh = (unsigned short*)((char*)d_ws + 8192);
    unsigned short* ebm = ebh + KEMB * DDIM;
    unsigned short* ebl = ebm + KEMB * DDIM;

    vq_init<<<1, 512, 0, stream>>>(emb, counts, hnorms, loss_acc, ebh, ebm, ebl);
    vq_main<<<512, 256, 0, stream>>>(in, emb, ebh, ebm, ebl, hnorms, counts, loss_acc, dout);
    vq_fin<<<1, 512, 0, stream>>>(counts, loss_acc, dout);
}

// Round 5
// 184.151 us; speedup vs baseline: 1.9416x; 1.3684x over previous
//
#include <hip/hip_runtime.h>
#include <math.h>

// Problem constants
#define NPIX   131072      // B*H*W = 32*64*64
#define KEMB   512
#define DDIM   64
#define HW     4096        // H*W
#define BSTRIDE 262144     // C*H*W

// d_out flat layout (float32): [loss(1) | out(8388608) | perplexity(1) | indices(131072)]
#define OUT_OFF  1
#define PERP_OFF 8388609
#define IDX_OFF  8388610

typedef __attribute__((ext_vector_type(8))) short bf16x8;   // 8 bf16 = 4 VGPRs (MFMA A/B frag)
typedef __attribute__((ext_vector_type(4))) float f32x4;    // MFMA C/D frag

__device__ __forceinline__ unsigned short bf16_rtne(float f) {
    unsigned int u = __float_as_uint(f);
    u += 0x7FFFu + ((u >> 16) & 1u);
    return (unsigned short)(u >> 16);
}
__device__ __forceinline__ float bf16_to_f(unsigned short h) {
    return __uint_as_float(((unsigned int)h) << 16);
}

// ws layout: [0,2048) int counts | [2048,4096) float hnorms | [4096] loss |
//            [8192) ebh ushort[32768] | +64KB ebm | +64KB ebl
// 8 blocks x 64 threads: thread = one code (same serial per-code math as the
// passing R4 kernel — float4 chain for the norm — just spread over 8 CUs).
__global__ void vq_init(const float* __restrict__ emb, int* __restrict__ counts,
                        float* __restrict__ hnorms, float* __restrict__ loss_acc,
                        unsigned short* __restrict__ ebh, unsigned short* __restrict__ ebm,
                        unsigned short* __restrict__ ebl) {
    int k = blockIdx.x * 64 + threadIdx.x;   // 512 codes
    counts[k] = 0;
    const float4* row4 = (const float4*)(emb + k * DDIM);
    float s = 0.f;
#pragma unroll
    for (int i = 0; i < 16; ++i) {
        float4 v = row4[i];
        s += v.x * v.x + v.y * v.y + v.z * v.z + v.w * v.w;
    }
    hnorms[k] = 0.5f * s;
    const float* row = emb + k * DDIM;
#pragma unroll
    for (int c = 0; c < DDIM; ++c) {
        float x = row[c];
        unsigned short h = bf16_rtne(x);
        float r1 = x - bf16_to_f(h);          // exact (Sterbenz)
        unsigned short m = bf16_rtne(r1);
        float r2 = r1 - bf16_to_f(m);         // exact
        unsigned short l = bf16_rtne(r2);
        ebh[k * DDIM + c] = h; ebm[k * DDIM + c] = m; ebl[k * DDIM + c] = l;
    }
    if (k == 0) *loss_acc = 0.f;
}

// Wave owns 64 pixels (4 B-tiles of N=16). Codes stream as A-tiles (M=16).
// Approx score = 0.5||e||^2 - x.e via triple-bf16 MFMA -> top-2 candidates,
// then exact fp32 rescore of the 2 candidates (matches np's fp32 decisions).
// NOTE: all fragment arrays use compile-time indices only (fully unrolled) —
// a runtime-indexed local array goes to scratch (R4: 429 MB of spill traffic).
__global__ __launch_bounds__(256, 2) void vq_main(
    const float* __restrict__ in, const float* __restrict__ emb,
    const unsigned short* __restrict__ ebh, const unsigned short* __restrict__ ebm,
    const unsigned short* __restrict__ ebl,
    const float* __restrict__ hnorms, int* __restrict__ counts,
    float* __restrict__ loss_acc, float* __restrict__ dout)
{
    __shared__ int hist[KEMB];
    const int t = threadIdx.x;
    hist[t] = 0; hist[t + 256] = 0;
    __syncthreads();

    const int lane = t & 63;
    const int wid  = t >> 6;
    const int quad = lane >> 4;
    const int col  = lane & 15;
    const int b    = blockIdx.x >> 4;
    const int p0   = ((blockIdx.x & 15) << 8) | (wid << 6);   // first of 64 pixels
    const float* xb = in + b * BSTRIDE;

    // ---- Build x B-fragments: B[n=col][k=quad*8+j], xf[split][ptile][kstep] ----
    bf16x8 xf[3][4][2];
#pragma unroll
    for (int tt = 0; tt < 4; ++tt) {
#pragma unroll
        for (int s = 0; s < 2; ++s) {
            const int pp = p0 + tt * 16 + col;
            const int c0 = s * 32 + quad * 8;
            bf16x8 vh, vm, vl;
#pragma unroll
            for (int j = 0; j < 8; ++j) {
                float x = xb[(c0 + j) * HW + pp];
                unsigned short h = bf16_rtne(x);
                float r1 = x - bf16_to_f(h);
                unsigned short m = bf16_rtne(r1);
                float r2 = r1 - bf16_to_f(m);
                unsigned short l = bf16_rtne(r2);
                vh[j] = (short)h; vm[j] = (short)m; vl[j] = (short)l;
            }
            xf[0][tt][s] = vh; xf[1][tt][s] = vm; xf[2][tt][s] = vl;
        }
    }

    const int arow = col * DDIM + quad * 8;   // lane offset within a code-tile (ushorts)

    // top-2 tracking per pixel-tile (lex order on (value, index))
    float v1[4], v2[4]; int k1[4], k2[4];
#pragma unroll
    for (int tt = 0; tt < 4; ++tt) {
        v1[tt] = 3.402823466e38f; v2[tt] = 3.402823466e38f; k1[tt] = 0; k2[tt] = 0;
    }

#pragma unroll 2
    for (int ct = 0; ct < 32; ++ct) {
        const int off = ct * 16 * DDIM + arow;
        // Single-buffered A fragments, static names (registers, not scratch).
        const bf16x8 Ah0 = *(const bf16x8*)(ebh + off);
        const bf16x8 Ah1 = *(const bf16x8*)(ebh + off + 32);
        const bf16x8 Am0 = *(const bf16x8*)(ebm + off);
        const bf16x8 Am1 = *(const bf16x8*)(ebm + off + 32);
        const bf16x8 Al0 = *(const bf16x8*)(ebl + off);
        const bf16x8 Al1 = *(const bf16x8*)(ebl + off + 32);

        f32x4 acc[4];
#pragma unroll
        for (int tt = 0; tt < 4; ++tt) acc[tt] = (f32x4){0.f, 0.f, 0.f, 0.f};

        // 6 split-products per k-step: hh, hm, mh, hl, lh, mm
#pragma unroll
        for (int tt = 0; tt < 4; ++tt) {
            acc[tt] = __builtin_amdgcn_mfma_f32_16x16x32_bf16(Ah0, xf[0][tt][0], acc[tt], 0, 0, 0);
            acc[tt] = __builtin_amdgcn_mfma_f32_16x16x32_bf16(Ah0, xf[1][tt][0], acc[tt], 0, 0, 0);
            acc[tt] = __builtin_amdgcn_mfma_f32_16x16x32_bf16(Am0, xf[0][tt][0], acc[tt], 0, 0, 0);
            acc[tt] = __builtin_amdgcn_mfma_f32_16x16x32_bf16(Ah0, xf[2][tt][0], acc[tt], 0, 0, 0);
            acc[tt] = __builtin_amdgcn_mfma_f32_16x16x32_bf16(Al0, xf[0][tt][0], acc[tt], 0, 0, 0);
            acc[tt] = __builtin_amdgcn_mfma_f32_16x16x32_bf16(Am0, xf[1][tt][0], acc[tt], 0, 0, 0);
            acc[tt] = __builtin_amdgcn_mfma_f32_16x16x32_bf16(Ah1, xf[0][tt][1], acc[tt], 0, 0, 0);
            acc[tt] = __builtin_amdgcn_mfma_f32_16x16x32_bf16(Ah1, xf[1][tt][1], acc[tt], 0, 0, 0);
            acc[tt] = __builtin_amdgcn_mfma_f32_16x16x32_bf16(Am1, xf[0][tt][1], acc[tt], 0, 0, 0);
            acc[tt] = __builtin_amdgcn_mfma_f32_16x16x32_bf16(Ah1, xf[2][tt][1], acc[tt], 0, 0, 0);
            acc[tt] = __builtin_amdgcn_mfma_f32_16x16x32_bf16(Al1, xf[0][tt][1], acc[tt], 0, 0, 0);
            acc[tt] = __builtin_amdgcn_mfma_f32_16x16x32_bf16(Am1, xf[1][tt][1], acc[tt], 0, 0, 0);
        }

        const f32x4 hn = *(const f32x4*)(hnorms + ct * 16 + quad * 4);
#pragma unroll
        for (int tt = 0; tt < 4; ++tt) {
#pragma unroll
            for (int r = 0; r < 4; ++r) {
                const float sc = hn[r] - acc[tt][r];
                const int   kk = ct * 16 + quad * 4 + r;
                if (sc < v1[tt]) { v2[tt] = v1[tt]; k2[tt] = k1[tt]; v1[tt] = sc; k1[tt] = kk; }
                else if (sc < v2[tt]) { v2[tt] = sc; k2[tt] = kk; }
            }
        }
    }

    // Cross-quad top-2 merge (lanes l, l^16, l^32 share pixel-col)
#pragma unroll
    for (int tt = 0; tt < 4; ++tt) {
#pragma unroll
        for (int off = 16; off <= 32; off <<= 1) {
            float w1 = __shfl_xor(v1[tt], off, 64); int j1 = __shfl_xor(k1[tt], off, 64);
            float w2 = __shfl_xor(v2[tt], off, 64); int j2 = __shfl_xor(k2[tt], off, 64);
            bool aF = (v1[tt] < w1) || (v1[tt] == w1 && k1[tt] < j1);
            float t1 = aF ? v1[tt] : w1;  int u1 = aF ? k1[tt] : j1;
            float tl = aF ? w1 : v1[tt];  int ul = aF ? j1 : k1[tt];      // loser of firsts
            bool bS = (v2[tt] < w2) || (v2[tt] == w2 && k2[tt] < j2);
            float tc = bS ? v2[tt] : w2;  int uc = bS ? k2[tt] : j2;      // better of seconds
            bool lS = (tl < tc) || (tl == tc && ul < uc);
            v1[tt] = t1; k1[tt] = u1;
            v2[tt] = lS ? tl : tc; k2[tt] = lS ? ul : uc;
        }
    }
    const int kA = k1[quad], kB = k2[quad];   // lane's own pixel = p0 + lane
    const int pp = p0 + lane;

    // Reload x (fp32, coalesced) for exact rescore + epilogue
    float x[DDIM];
#pragma unroll
    for (int c = 0; c < DDIM; ++c) x[c] = xb[c * HW + pp];

    // Exact fp32 rescore: byte-identical math to the R2-passing kernel
    const float4* eA = (const float4*)(emb + kA * DDIM);
    const float4* eB = (const float4*)(emb + kB * DDIM);
    float a0 = hnorms[kA], a1 = 0.f, a2 = 0.f, a3 = 0.f;
    float b0 = hnorms[kB], b1 = 0.f, b2 = 0.f, b3 = 0.f;
#pragma unroll
    for (int i = 0; i < 16; ++i) {
        float4 ea = eA[i], eb = eB[i];
        const int c = i * 4;
        a0 = fmaf(-x[c + 0], ea.x, a0);
        a1 = fmaf(-x[c + 1], ea.y, a1);
        a2 = fmaf(-x[c + 2], ea.z, a2);
        a3 = fmaf(-x[c + 3], ea.w, a3);
        b0 = fmaf(-x[c + 0], eb.x, b0);
        b1 = fmaf(-x[c + 1], eb.y, b1);
        b2 = fmaf(-x[c + 2], eb.z, b2);
        b3 = fmaf(-x[c + 3], eb.w, b3);
    }
    const float dA = (a0 + a1) + (a2 + a3);
    const float dB = (b0 + b1) + (b2 + b3);
    const int myk = (dB < dA || (dB == dA && kB < kA)) ? kB : kA;

    dout[IDX_OFF + b * HW + pp] = (float)myk;
    atomicAdd(&hist[myk], 1);

    // Epilogue: gather chosen code, ST output + loss (reference rounding x+(q-x))
    const float4* qrow = (const float4*)(emb + myk * DDIM);
    float* ob = dout + OUT_OFF + b * BSTRIDE;
    float lsum = 0.f;
#pragma unroll
    for (int i = 0; i < 16; ++i) {
        float4 qv = qrow[i];
        const int c = i * 4;
        float d0 = qv.x - x[c + 0];
        float d1 = qv.y - x[c + 1];
        float d2 = qv.z - x[c + 2];
        float d3 = qv.w - x[c + 3];
        lsum += d0 * d0 + d1 * d1 + d2 * d2 + d3 * d3;
        ob[(c + 0) * HW + pp] = x[c + 0] + d0;
        ob[(c + 1) * HW + pp] = x[c + 1] + d1;
        ob[(c + 2) * HW + pp] = x[c + 2] + d2;
        ob[(c + 3) * HW + pp] = x[c + 3] + d3;
    }
    for (int off = 32; off > 0; off >>= 1) lsum += __shfl_down(lsum, off, 64);
    if (lane == 0) atomicAdd(loss_acc, lsum);

    __syncthreads();
    for (int k = t; k < KEMB; k += 256) {
        int v = hist[k];
        if (v) atomicAdd(&counts[k], v);
    }
}

__global__ void vq_fin(const int* __restrict__ counts,
                       const float* __restrict__ loss_acc,
                       float* __restrict__ dout) {
    __shared__ float red[KEMB];
    int k = threadIdx.x;            // 512 threads
    float c = (float)counts[k];
    float pa = c / (float)NPIX;
    red[k] = pa * logf(pa + 1e-10f);
    __syncthreads();
    for (int s = 256; s > 0; s >>= 1) {
        if (k < s) red[k] += red[k + s];
        __syncthreads();
    }
    if (k == 0) {
        dout[PERP_OFF] = expf(-red[0]);
        dout[0] = 0.25f * (*loss_acc) / 8388608.0f;
    }
}

extern "C" void kernel_launch(void* const* d_in, const int* in_sizes, int n_in,
                              void* d_out, int out_size, void* d_ws, size_t ws_size,
                              hipStream_t stream) {
    const float* in  = (const float*)d_in[0];   // 8388608 elems
    const float* emb = (const float*)d_in[1];   // 32768 elems
    float* dout = (float*)d_out;
    int*   counts   = (int*)d_ws;
    float* hnorms   = (float*)((char*)d_ws + 2048);
    float* loss_acc = (float*)((char*)d_ws + 4096);
    unsigned short* ebh = (unsigned short*)((char*)d_ws + 8192);
    unsigned short* ebm = ebh + KEMB * DDIM;
    unsigned short* ebl = ebm + KEMB * DDIM;

    vq_init<<<8, 64, 0, stream>>>(emb, counts, hnorms, loss_acc, ebh, ebm, ebl);
    vq_main<<<512, 256, 0, stream>>>(in, emb, ebh, ebm, ebl, hnorms, counts, loss_acc, dout);
    vq_fin<<<1, 512, 0, stream>>>(counts, loss_acc, dout);
}